// Round 10
// baseline (2498.484 us; speedup 1.0000x reference)
//
#include <hip/hip_runtime.h>
#include <math.h>

#define TT 150
#define BB 64
#define DD 2000
#define SS 3000
#define EE 100000
#define EEPAD 124160   // >= EE + SS*7 (arcs padded per-state to multiple of 8)
#define RESC 16
#define NSLOT 9
#define RESCC 0x1p-46f // exact pow2 rescale every 16 steps (growth ~7.42^16 ~= 2^46.3)

#define NT 1024        // threads per block (16 waves)
#define NBLK 256       // 1 block per CU (forced by LDS) -> exactly 32 blocks per XCD
#define NG 8           // groups = measured XCDs, 8 batch lanes each
#define GB 32          // blocks per group
#define CAP 4608       // LDS arc slots per block (balanced slice ~3.9k)
#define ASTRD 12288    // dwords per alpha buffer per group (3072 rows x 4)
#define NSTMAX 512
#define FLGSTR 32      // dwords between flags (128 B)
#define NEXB 32

// dynamic LDS layout (bytes)
#define OFF_ARC    0                 // 4608*8  = 36864
#define OFF_ALPHA  36864             // 3072*16 = 49152 (16-aligned)
#define OFF_EX     86016             // 2048*16 = 32768 (16-aligned)
#define OFF_RBP    118784            // 513*4 -> 2064
#define OFF_RED    120848            // 16*8*4  = 512
#define OFF_SH     121360            // 16
#define DYNLDS     121600

struct __align__(8) ArcT2 { unsigned idx; float ew; };   // idx = from | (pdf<<16)

typedef unsigned uv4 __attribute__((ext_vector_type(4)));

__device__ inline float b2f(unsigned short u) {
    union { unsigned u32; float f; } x; x.u32 = ((unsigned)u) << 16; return x.f;
}
__device__ inline unsigned short f2b(float f) {
    union { float f; unsigned u; } x; x.f = f;
    unsigned r = x.u + 0x7FFF + ((x.u >> 16) & 1);       // RNE, positive finite only
    return (unsigned short)(r >> 16);
}
__device__ inline float u2f(unsigned u) {
    union { unsigned u32; float f; } x; x.u32 = u; return x.f;
}
__device__ inline unsigned pack2(float a, float b) {
    return (unsigned)f2b(a) | ((unsigned)f2b(b) << 16);
}

// ---------------- setup kernels ----------------
__global__ void k_setup(int* __restrict__ counts, unsigned* __restrict__ flags,
                        float* __restrict__ partial, ArcT2* __restrict__ arcs,
                        unsigned* __restrict__ tickets)
{
    int i = blockIdx.x * blockDim.x + threadIdx.x;
    if (i < SS) counts[i] = 0;
    if (i < 2 * NBLK * FLGSTR) flags[i] = 0u;
    if (i < NG * 8) partial[i] = 0.f;
    if (i < 8) tickets[i] = 0u;
    if (i < EEPAD) { ArcT2 z; z.idx = 0; z.ew = 0.f; arcs[i] = z; }
}

__global__ void k_hist(const int* __restrict__ to_state, int* __restrict__ counts)
{
    int e = blockIdx.x * blockDim.x + threadIdx.x;
    if (e < EE) atomicAdd(&counts[to_state[e]], 1);
}

// prefix over counts padded to multiple of 8
__global__ void k_scan(const int* __restrict__ counts, int* __restrict__ rp,
                       int* __restrict__ cur)
{
    __shared__ int ls[1024];
    int tid = threadIdx.x;
    int s0 = tid * 3;
    int a0 = (s0 + 0 < SS) ? ((counts[s0 + 0] + 7) & ~7) : 0;
    int a1 = (s0 + 1 < SS) ? ((counts[s0 + 1] + 7) & ~7) : 0;
    int a2 = (s0 + 2 < SS) ? ((counts[s0 + 2] + 7) & ~7) : 0;
    int tsum = a0 + a1 + a2;
    ls[tid] = tsum;
    __syncthreads();
    for (int off = 1; off < 1024; off <<= 1) {
        int v = ls[tid];
        int add = (tid >= off) ? ls[tid - off] : 0;
        __syncthreads();
        ls[tid] = v + add;
        __syncthreads();
    }
    int excl = ls[tid] - tsum;
    if (s0 + 0 < SS) { rp[s0 + 0] = excl; cur[s0 + 0] = excl; }
    excl += a0;
    if (s0 + 1 < SS) { rp[s0 + 1] = excl; cur[s0 + 1] = excl; }
    excl += a1;
    if (s0 + 2 < SS) { rp[s0 + 2] = excl; cur[s0 + 2] = excl; }
    if (tid == 1023) rp[SS] = ls[1023];
}

// arc-balanced split into GB slices
__global__ void k_split(const int* __restrict__ rp, int* __restrict__ split)
{
    int j = threadIdx.x;
    if (j > GB) return;
    if (j == 0)  { split[0] = 0; return; }
    if (j == GB) { split[GB] = SS; return; }
    long long total = rp[SS];
    int target = (int)((total * j) / GB);
    int lo = 0, hi = SS;
    while (lo < hi) { int mid = (lo + hi) >> 1; if (rp[mid] >= target) hi = mid; else lo = mid + 1; }
    split[j] = lo;
}

__global__ void k_scatter(const int* __restrict__ from_state, const int* __restrict__ to_state,
                          const int* __restrict__ pdf_id, const float* __restrict__ trans_logw,
                          int* __restrict__ cur, ArcT2* __restrict__ arcs)
{
    int e = blockIdx.x * blockDim.x + threadIdx.x;
    if (e >= EE) return;
    int s = to_state[e];
    int pos = atomicAdd(&cur[s], 1);
    ArcT2 a;
    a.idx = (unsigned)from_state[e] | ((unsigned)pdf_id[e] << 16);
    a.ew = __expf(trans_logw[e]);
    arcs[pos] = a;
}

// ---------------- cooperative mega-kernel, measured-XCD groups ----------------
__global__ void __launch_bounds__(NT, 4) k_coop(
    const ArcT2* __restrict__ arcs, const int* __restrict__ rp,
    const int* __restrict__ split,
    const float* __restrict__ input, const float* __restrict__ init_logp,
    const float* __restrict__ final_logp,
    float* __restrict__ partial,         // [NG][8]
    unsigned* __restrict__ A_all,        // [NG][2][ASTRD] rows of 4 dwords (8xbf16)
    unsigned* __restrict__ flags,        // [2][NBLK][FLGSTR]
    unsigned* __restrict__ tickets,      // [8]
    float* __restrict__ out)
{
    extern __shared__ char dsm[];
    ArcT2*    larc  = (ArcT2*)(dsm + OFF_ARC);
    unsigned* la32  = (unsigned*)(dsm + OFF_ALPHA);   // [3000][4] packed bf16 x8
    unsigned* lex32 = (unsigned*)(dsm + OFF_EX);      // [2000][4]
    int*      rbp   = (int*)(dsm + OFF_RBP);
    float*    redf  = (float*)(dsm + OFF_RED);
    unsigned* sh    = (unsigned*)(dsm + OFF_SH);

    int tid = threadIdx.x, bid = blockIdx.x;
    int lane = tid & 63, wave = tid >> 6;
    int oct = lane >> 3, sub = lane & 7;

    unsigned* stepf = flags;
    unsigned* auxf  = flags + (size_t)NBLK * FLGSTR;

    // ---- measure XCD + take group ticket (placement-independent grouping) ----
    if (tid == 0) {
        unsigned x = __builtin_amdgcn_s_getreg(6164) & 7u;   // HW_REG_XCC_ID (verified r8)
        unsigned t = __hip_atomic_fetch_add(&tickets[x], 1u, __ATOMIC_RELAXED,
                                            __HIP_MEMORY_SCOPE_AGENT);
        sh[0] = x; sh[1] = t;
        __hip_atomic_store(auxf + (size_t)bid * FLGSTR, 1u,
                           __ATOMIC_RELAXED, __HIP_MEMORY_SCOPE_AGENT);
    }
    // global aux barrier #1: all 256 blocks ticketed
    if (wave == 0) {
        while (true) {
            unsigned ok = 1;
            #pragma unroll
            for (int r = 0; r < 4; ++r) {
                unsigned v = __hip_atomic_load(auxf + (size_t)(lane * 4 + r) * FLGSTR,
                                               __ATOMIC_RELAXED, __HIP_MEMORY_SCOPE_AGENT);
                ok &= (v >= 1u);
            }
            if (__ballot(ok != 0) == ~0ULL) break;
            __builtin_amdgcn_s_sleep(1);
        }
    }
    __syncthreads();
    // validity: every XCD group must have exactly 32 members
    if (tid == 0) {
        unsigned ok = 1;
        for (int q = 0; q < 8; ++q)
            ok &= (__hip_atomic_load(&tickets[q], __ATOMIC_RELAXED,
                                     __HIP_MEMORY_SCOPE_AGENT) == (unsigned)GB);
        sh[2] = ok;
    }
    __syncthreads();
    const bool fast = (sh[2] != 0);
    int g = fast ? (int)sh[0] : (bid & 7);
    int j = fast ? (int)(sh[1] & 31) : (bid >> 3);
    __syncthreads();

    unsigned* Ag       = A_all + (size_t)g * (2 * ASTRD);
    unsigned* myflag   = stepf + (size_t)(g * GB + j) * FLGSTR;
    unsigned* grpflag  = stepf + (size_t)(g * GB) * FLGSTR;
    unsigned* myflag2  = auxf + (size_t)(g * GB + j) * FLGSTR;
    unsigned* grpflag2 = auxf + (size_t)(g * GB) * FLGSTR;

    int s0 = split[j], s1 = split[j + 1];
    int nst = s1 - s0;
    if (nst > NSTMAX) nst = NSTMAX;                  // safety (never expected)

    // ---- stage rp slice + arcs to LDS; alpha0 (own slice) ----
    for (int i = tid; i <= nst; i += NT) rbp[i] = rp[s0 + i];
    __syncthreads();
    int rb0 = rbp[0];
    {
        int staged = rbp[nst] - rb0; if (staged > CAP) staged = CAP;
        for (int i = tid; i < staged; i += NT) larc[i] = arcs[rb0 + i];
    }
    for (int i = tid; i < nst; i += NT) {
        int s = s0 + i;
        unsigned short h = f2b(__expf(init_logp[s]));
        unsigned pk = (unsigned)h | ((unsigned)h << 16);
        if (fast) {
            uv4 v; v.x = pk; v.y = pk; v.z = pk; v.w = pk;
            *(uv4*)(Ag + s * 4) = v;
        } else {
            unsigned long long q = (unsigned long long)pk | ((unsigned long long)pk << 32);
            __hip_atomic_store((unsigned long long*)(Ag + s * 4), q,
                               __ATOMIC_RELAXED, __HIP_MEMORY_SCOPE_AGENT);
            __hip_atomic_store((unsigned long long*)(Ag + s * 4) + 1, q,
                               __ATOMIC_RELAXED, __HIP_MEMORY_SCOPE_AGENT);
        }
    }
    __syncthreads();                                 // larc ready; alpha0 stores drained
    if (tid == 0)
        __hip_atomic_store(myflag2, 2u, __ATOMIC_RELAXED, __HIP_MEMORY_SCOPE_AGENT);
    {   // ex frame 0 (overlaps other blocks' arrival)
        const float* fr = input + (size_t)(g * 8) * DD;
        for (int d = tid; d < DD; d += NT) {
            uv4 v;
            v.x = pack2(__expf(fr[0 * DD + d]), __expf(fr[1 * DD + d]));
            v.y = pack2(__expf(fr[2 * DD + d]), __expf(fr[3 * DD + d]));
            v.z = pack2(__expf(fr[4 * DD + d]), __expf(fr[5 * DD + d]));
            v.w = pack2(__expf(fr[6 * DD + d]), __expf(fr[7 * DD + d]));
            *(uv4*)(lex32 + d * 4) = v;
        }
    }
    if (wave == 0) {                                 // group barrier #2: alpha0 visible
        while (true) {
            unsigned v = 2;
            if (lane < GB)
                v = __hip_atomic_load(grpflag2 + lane * FLGSTR, __ATOMIC_RELAXED,
                                      __HIP_MEMORY_SCOPE_AGENT);
            if (__ballot(v >= 2) == ~0ULL) break;
            __builtin_amdgcn_s_sleep(1);
        }
    }
    __syncthreads();

    float vf[8];
    #pragma unroll
    for (int q = 0; q < 8; ++q) vf[q] = 0.f;

    unsigned ep = 0;

    // ---- 150 steps ----
    for (int k = 0; k < TT; ++k) {
        const unsigned* Ap32 = Ag + (k & 1) * ASTRD;
        unsigned*       An32 = Ag + ((k + 1) & 1) * ASTRD;
        bool last = (k == TT - 1);
        bool resc = (((k + 1) & (RESC - 1)) == 0);

        // phase A: alpha_k (48 KB) L2 -> LDS
        if (fast) {
            const uv4* Ap128 = (const uv4*)Ap32;
            for (int idx = tid; idx < SS; idx += NT) {
                uv4 v = *(volatile const uv4*)(Ap128 + idx);   // volatile -> sc0
                *((uv4*)la32 + idx) = v;
            }
        } else {
            const unsigned long long* Ap64 = (const unsigned long long*)Ap32;
            for (int idx = tid; idx < SS * 2; idx += NT) {
                unsigned long long v = __hip_atomic_load(Ap64 + idx, __ATOMIC_RELAXED,
                                                         __HIP_MEMORY_SCOPE_AGENT);
                la32[idx * 2 + 0] = (unsigned)v;
                la32[idx * 2 + 1] = (unsigned)(v >> 32);
            }
        }
        __syncthreads();

        // phase B: gather own states; lane=(oct=state slot, sub=arc sub)
        for (int base = 0; base < nst; base += 128) {
            int li = base + oct * 16 + wave;
            bool has = (li < nst);
            float acc[8];
            #pragma unroll
            for (int q = 0; q < 8; ++q) acc[q] = 0.f;
            int sg = 0;
            if (has) {
                sg = s0 + li;
                int ra = rbp[li], re = rbp[li + 1];
                int nit = (re - ra) >> 3;
                if (re - rb0 <= CAP) {
                    int bix = ra - rb0 + sub;
                    for (int t = 0; t < nit; ++t) {
                        ArcT2 a = larc[bix + t * 8];
                        uv4 av = *(const uv4*)(la32 + (a.idx & 0xFFFF) * 4);
                        uv4 ev = *(const uv4*)(lex32 + (a.idx >> 16) * 4);
                        float ew = a.ew;
                        #pragma unroll
                        for (int q = 0; q < 4; ++q) {
                            unsigned au = av[q], eu = ev[q];
                            acc[2 * q + 0] = fmaf(u2f(au << 16), ew * u2f(eu << 16),
                                                  acc[2 * q + 0]);
                            acc[2 * q + 1] = fmaf(u2f(au & 0xFFFF0000u),
                                                  ew * u2f(eu & 0xFFFF0000u),
                                                  acc[2 * q + 1]);
                        }
                    }
                } else {
                    for (int t = 0; t < nit; ++t) {  // safety overflow path
                        ArcT2 a = arcs[ra + t * 8 + sub];
                        uv4 av = *(const uv4*)(la32 + (a.idx & 0xFFFF) * 4);
                        uv4 ev = *(const uv4*)(lex32 + (a.idx >> 16) * 4);
                        float ew = a.ew;
                        #pragma unroll
                        for (int q = 0; q < 4; ++q) {
                            unsigned au = av[q], eu = ev[q];
                            acc[2 * q + 0] = fmaf(u2f(au << 16), ew * u2f(eu << 16),
                                                  acc[2 * q + 0]);
                            acc[2 * q + 1] = fmaf(u2f(au & 0xFFFF0000u),
                                                  ew * u2f(eu & 0xFFFF0000u),
                                                  acc[2 * q + 1]);
                        }
                    }
                }
            }
            #pragma unroll
            for (int q = 0; q < 8; ++q) {
                acc[q] += __shfl_xor(acc[q], 1, 64);
                acc[q] += __shfl_xor(acc[q], 2, 64);
                acc[q] += __shfl_xor(acc[q], 4, 64);
            }
            if (has && sub == 0) {
                if (resc) {
                    #pragma unroll
                    for (int q = 0; q < 8; ++q) acc[q] *= RESCC;
                }
                if (last) {
                    float ef = __expf(final_logp[sg]);
                    #pragma unroll
                    for (int q = 0; q < 8; ++q) vf[q] = fmaf(acc[q], ef, vf[q]);
                } else {
                    uv4 pk4;
                    pk4.x = pack2(acc[0], acc[1]);
                    pk4.y = pack2(acc[2], acc[3]);
                    pk4.z = pack2(acc[4], acc[5]);
                    pk4.w = pack2(acc[6], acc[7]);
                    if (fast) {
                        *(uv4*)(An32 + sg * 4) = pk4;
                    } else {
                        unsigned long long lo = (unsigned long long)pk4.x |
                                                ((unsigned long long)pk4.y << 32);
                        unsigned long long hi = (unsigned long long)pk4.z |
                                                ((unsigned long long)pk4.w << 32);
                        __hip_atomic_store((unsigned long long*)(An32 + sg * 4), lo,
                                           __ATOMIC_RELAXED, __HIP_MEMORY_SCOPE_AGENT);
                        __hip_atomic_store((unsigned long long*)(An32 + sg * 4) + 1, hi,
                                           __ATOMIC_RELAXED, __HIP_MEMORY_SCOPE_AGENT);
                    }
                }
            }
        }
        if (last) break;
        __syncthreads();                             // stores drained (vmcnt 0)
        ++ep;
        if (tid == 0) {
            if (fast) *(volatile unsigned*)myflag = ep;
            else __hip_atomic_store(myflag, ep, __ATOMIC_RELAXED, __HIP_MEMORY_SCOPE_AGENT);
        }
        {   // ex_{k+1} (independent of alpha) — overlaps others' arrival
            const float* fr = input + (size_t)((k + 1) * BB + g * 8) * DD;
            for (int d = tid; d < DD; d += NT) {
                uv4 v;
                v.x = pack2(__expf(fr[0 * DD + d]), __expf(fr[1 * DD + d]));
                v.y = pack2(__expf(fr[2 * DD + d]), __expf(fr[3 * DD + d]));
                v.z = pack2(__expf(fr[4 * DD + d]), __expf(fr[5 * DD + d]));
                v.w = pack2(__expf(fr[6 * DD + d]), __expf(fr[7 * DD + d]));
                *(uv4*)(lex32 + d * 4) = v;
            }
        }
        if (wave == 0) {
            while (true) {
                unsigned v = ep;
                if (lane < GB) {
                    v = fast ? *(volatile const unsigned*)(grpflag + lane * FLGSTR)
                             : __hip_atomic_load(grpflag + lane * FLGSTR, __ATOMIC_RELAXED,
                                                 __HIP_MEMORY_SCOPE_AGENT);
                }
                if (__ballot(v >= ep) == ~0ULL) break;
                __builtin_amdgcn_s_sleep(1);
            }
        }
        __syncthreads();
    }

    // ---- epilogue: reduce objf (8 batch) across block, then group ----
    #pragma unroll
    for (int q = 0; q < 8; ++q) {
        float v = vf[q];
        v += __shfl_xor(v, 1, 64);
        v += __shfl_xor(v, 2, 64);
        v += __shfl_xor(v, 4, 64);
        v += __shfl_xor(v, 8, 64);
        v += __shfl_xor(v, 16, 64);
        v += __shfl_xor(v, 32, 64);
        if (lane == 0) redf[wave * 8 + q] = v;
    }
    __syncthreads();
    if (tid < 8) {
        float S = 0.f;
        #pragma unroll
        for (int w = 0; w < 16; ++w) S += redf[w * 8 + tid];
        __hip_atomic_fetch_add(&partial[g * 8 + tid], S, __ATOMIC_RELAXED,
                               __HIP_MEMORY_SCOPE_AGENT);
    }
    __syncthreads();
    if (tid == 0)
        __hip_atomic_store(myflag2, 3u, __ATOMIC_RELAXED, __HIP_MEMORY_SCOPE_AGENT);
    if (j == 0) {
        if (wave == 0) {
            while (true) {
                unsigned v = 3;
                if (lane < GB)
                    v = __hip_atomic_load(grpflag2 + lane * FLGSTR, __ATOMIC_RELAXED,
                                          __HIP_MEMORY_SCOPE_AGENT);
                if (__ballot(v >= 3) == ~0ULL) break;
                __builtin_amdgcn_s_sleep(1);
            }
        }
        __syncthreads();
        if (tid < 8) {
            float S = __hip_atomic_load(&partial[g * 8 + tid], __ATOMIC_RELAXED,
                                        __HIP_MEMORY_SCOPE_AGENT);
            float lg = logf(S) + (float)(NSLOT * 46) * 0.69314718055994531f;
            atomicAdd(out, lg);
        }
    }
}

// ---------------- fallback path (round-8 per-step kernels, proven) ----------------
template <int THREADS>
__device__ inline void transpose_exp_t(const float* __restrict__ frame,
                                       unsigned short* __restrict__ dst,
                                       int tile_id, int tid, unsigned short* smem)
{
    int d0 = tile_id * 64;
    #pragma unroll
    for (int it = 0; it < 4096 / THREADS; ++it) {
        int idx = it * THREADS + tid;
        int dl = idx & 63, bl = idx >> 6;
        int d = d0 + dl;
        float v = 0.f;
        if (d < DD) v = __expf(frame[bl * DD + d]);
        smem[dl * 65 + bl] = f2b(v);
    }
    __syncthreads();
    #pragma unroll
    for (int it = 0; it < 4096 / THREADS; ++it) {
        int idx = it * THREADS + tid;
        int bo = idx & 63, dq = idx >> 6;
        int d = d0 + dq;
        if (d < DD) dst[(d << 6) + bo] = smem[dq * 65 + bo];
    }
    __syncthreads();
}

__global__ void k_initA(const float* __restrict__ init_logp,
                        unsigned short* __restrict__ A0, float* __restrict__ M2)
{
    int idx = blockIdx.x * blockDim.x + threadIdx.x;
    if (idx < SS * BB) A0[idx] = f2b(__expf(init_logp[idx >> 6]));
    if (idx < NSLOT * 16 * 64) M2[idx] = 0.f;
}

__global__ void k_transpose0(const float* __restrict__ frame, unsigned short* __restrict__ dst)
{
    __shared__ unsigned short tile[64 * 65];
    transpose_exp_t<256>(frame, dst, blockIdx.x, threadIdx.x, tile);
}

__global__ void __launch_bounds__(256) k_step(
    const ArcT2* __restrict__ arcs, const int* __restrict__ rp,
    const unsigned short* __restrict__ Ap, unsigned short* __restrict__ An,
    const unsigned short* __restrict__ ec,
    const float* __restrict__ frameNext, unsigned short* __restrict__ en,
    float* __restrict__ M2, int maxSlot, int useSlot)
{
    __shared__ unsigned short tile[64 * 65];
    __shared__ float part[256];
    __shared__ float rcpA[64];
    int tid = threadIdx.x, bid = blockIdx.x;
    if (bid >= SS) { transpose_exp_t<256>(frameNext, en, bid - SS, tid, tile); return; }
    int lane = tid & 63, wave = tid >> 6;
    if (useSlot >= 0 && wave == 0) {
        const float* Mrow = M2 + useSlot * (16 * 64);
        float m = Mrow[lane];
        #pragma unroll
        for (int g = 1; g < 16; ++g) m = fmaxf(m, Mrow[g * 64 + lane]);
        rcpA[lane] = 1.0f / m;
    }
    int rbeg = rp[bid], rend = rp[bid + 1];
    float acc = 0.f;
    for (int i = rbeg + wave; i < rend; i += 4) {
        ArcT2 a = arcs[i];
        int from = a.idx & 0xFFFF, pdf = a.idx >> 16;
        acc = fmaf(b2f(Ap[(from << 6) + lane]), a.ew * b2f(ec[(pdf << 6) + lane]), acc);
    }
    part[tid] = acc;
    __syncthreads();
    if (wave == 0) {
        float sum = part[lane] + part[64 + lane] + part[128 + lane] + part[192 + lane];
        if (useSlot >= 0) sum *= rcpA[lane];
        An[(bid << 6) + lane] = f2b(sum);
        if (maxSlot >= 0)
            atomicMax((unsigned*)&M2[maxSlot * (16 * 64) + (bid & 15) * 64 + lane],
                      __float_as_uint(sum));
    }
}

__global__ void k_fin(const unsigned short* __restrict__ AT, const float* __restrict__ final_logp,
                      const float* __restrict__ M2, float* __restrict__ out)
{
    __shared__ float red[1024];
    int tid = threadIdx.x;
    int lane = tid & 63, chunk = tid >> 6;
    float psum = 0.f;
    for (int s = chunk; s < SS; s += 16)
        psum += b2f(AT[(s << 6) + lane]) * __expf(final_logp[s]);
    red[tid] = psum;
    __syncthreads();
    if (tid < 64) {
        float sum = 0.f;
        #pragma unroll
        for (int c = 0; c < 16; ++c) sum += red[c * 64 + tid];
        float lg = logf(sum);
        #pragma unroll
        for (int r = 0; r < NSLOT; ++r) {
            const float* Mrow = M2 + r * (16 * 64);
            float m = Mrow[tid];
            #pragma unroll
            for (int g = 1; g < 16; ++g) m = fmaxf(m, Mrow[g * 64 + tid]);
            lg += logf(m);
        }
        #pragma unroll
        for (int off = 32; off > 0; off >>= 1) lg += __shfl_down(lg, off);
        if (tid == 0) out[0] = lg;
    }
}

extern "C" void kernel_launch(void* const* d_in, const int* in_sizes, int n_in,
                              void* d_out, int out_size, void* d_ws, size_t ws_size,
                              hipStream_t stream)
{
    const float* input      = (const float*)d_in[0];
    const float* trans_logw = (const float*)d_in[1];
    const float* init_logp  = (const float*)d_in[2];
    const float* final_logp = (const float*)d_in[3];
    const int*   from_state = (const int*)d_in[4];
    const int*   to_state   = (const int*)d_in[5];
    const int*   pdf_id     = (const int*)d_in[6];
    float* out = (float*)d_out;

    char* ws = (char*)d_ws;
    size_t off = 0;
    auto alloc = [&](size_t bytes) -> char* {
        char* p = ws + off;
        off = (off + bytes + 255) & ~(size_t)255;
        return p;
    };
    ArcT2* arcs  = (ArcT2*)alloc((size_t)EEPAD * sizeof(ArcT2));
    int* rp      = (int*)alloc((size_t)(SS + 1) * 4);
    int* cur     = (int*)alloc((size_t)SS * 4);
    int* counts  = (int*)alloc((size_t)SS * 4);
    int* split   = (int*)alloc((size_t)(GB + 1) * 4);
    unsigned* A_all = (unsigned*)alloc((size_t)NG * 2 * ASTRD * 4);
    float* partial  = (float*)alloc((size_t)NG * 8 * 4);
    unsigned* flags = (unsigned*)alloc((size_t)2 * NBLK * FLGSTR * 4);
    unsigned* tickets = (unsigned*)alloc((size_t)8 * 4);
    // fallback buffers
    unsigned short* A0  = (unsigned short*)alloc((size_t)SS * BB * 2);
    unsigned short* A1  = (unsigned short*)alloc((size_t)SS * BB * 2);
    unsigned short* EX0 = (unsigned short*)alloc((size_t)DD * BB * 2);
    unsigned short* EX1 = (unsigned short*)alloc((size_t)DD * BB * 2);
    float* M2    = (float*)alloc((size_t)NSLOT * 16 * 64 * 4);
    (void)ws_size; (void)in_sizes; (void)n_in; (void)out_size;

    k_setup<<<(EEPAD + 255) / 256, 256, 0, stream>>>(counts, flags, partial, arcs, tickets);
    k_hist<<<(EE + 255) / 256, 256, 0, stream>>>(to_state, counts);
    k_scan<<<1, 1024, 0, stream>>>(counts, rp, cur);
    k_split<<<1, 64, 0, stream>>>(rp, split);
    k_scatter<<<(EE + 255) / 256, 256, 0, stream>>>(from_state, to_state, pdf_id,
                                                    trans_logw, cur, arcs);
    hipMemsetAsync(d_out, 0, sizeof(float), stream);

    hipFuncSetAttribute((const void*)k_coop, hipFuncAttributeMaxDynamicSharedMemorySize,
                        DYNLDS);
    int nb = 0;
    hipOccupancyMaxActiveBlocksPerMultiprocessor(&nb, (const void*)k_coop, NT, DYNLDS);
    if (nb >= 1) {
        void* kp[11] = {
            (void*)&arcs, (void*)&rp, (void*)&split, (void*)&input, (void*)&init_logp,
            (void*)&final_logp, (void*)&partial, (void*)&A_all, (void*)&flags,
            (void*)&tickets, (void*)&out
        };
        hipError_t e = hipLaunchCooperativeKernel((const void*)k_coop, dim3(NBLK), dim3(NT),
                                                  kp, DYNLDS, stream);
        if (e == hipSuccess) return;
    }

    // Fallback: per-step kernels (bf16 state), known-passing structure.
    k_initA<<<(SS * BB + 255) / 256, 256, 0, stream>>>(init_logp, A0, M2);
    k_transpose0<<<NEXB, 256, 0, stream>>>(input, EX0);
    unsigned short* A[2]  = {A0, A1};
    unsigned short* EX[2] = {EX0, EX1};
    for (int k = 0; k < TT; ++k) {
        int kn = k + 1;
        int useSlot = (k > 0 && (k % RESC) == 0) ? (k / RESC - 1) : -1;
        int maxSlot = (kn < TT && (kn % RESC) == 0) ? (kn / RESC - 1) : -1;
        int grid = SS + ((kn < TT) ? NEXB : 0);
        const float* fnext = (kn < TT) ? (input + (size_t)kn * BB * DD) : nullptr;
        k_step<<<grid, 256, 0, stream>>>(arcs, rp, A[k & 1], A[kn & 1], EX[k & 1],
                                         fnext, EX[kn & 1], M2, maxSlot, useSlot);
    }
    k_fin<<<1, 1024, 0, stream>>>(A[TT & 1], final_logp, M2, out);
}

// Round 11
// 1022.066 us; speedup vs baseline: 2.4445x; 2.4445x over previous
//
#include <hip/hip_runtime.h>
#include <math.h>

#define TT 150
#define BB 64
#define DD 2000
#define SS 3000
#define EE 100000
#define EEPAD 124160   // >= EE + SS*7 (arcs padded per-state to multiple of 8)
#define RESC 16
#define NSLOT 9
#define RESCC 0x1p-46f // exact pow2 rescale every 16 steps (growth ~7.42^16 ~= 2^46.3)

#define NT 1024        // threads per block (16 waves)
#define NBLK 256       // 1 block per CU (forced by 121.6KB LDS) -> 32 blocks per XCD
#define NG 8           // groups = measured XCDs, 8 batch lanes each
#define GB 32          // blocks per group
#define CAP 4608       // LDS arc slots per block (balanced slice ~3.9k)
#define ASTRD 12288    // dwords per alpha buffer per group (3072 rows x 4)
#define NSTMAX 512
#define FLGSTR 32      // dwords between flags (128 B)

// dynamic LDS layout (bytes)
#define OFF_ARC    0                 // 4608*8  = 36864
#define OFF_ALPHA  36864             // 3072*16 = 49152 (16-aligned)
#define OFF_EX     86016             // 2048*16 = 32768 (16-aligned)
#define OFF_RBP    118784            // 513*4 -> 2064
#define OFF_RED    120848            // 16*8*4  = 512
#define OFF_SH     121360            // 16
#define DYNLDS     121600

struct __align__(8) ArcT2 { unsigned idx; float ew; };   // idx = from | (pdf<<16)

typedef unsigned uv4 __attribute__((ext_vector_type(4)));

__device__ inline unsigned short f2b(float f) {
    union { float f; unsigned u; } x; x.f = f;
    unsigned r = x.u + 0x7FFF + ((x.u >> 16) & 1);       // RNE, positive finite only
    return (unsigned short)(r >> 16);
}
__device__ inline float u2f(unsigned u) {
    union { unsigned u32; float f; } x; x.u32 = u; return x.f;
}
__device__ inline unsigned pack2(float a, float b) {
    return (unsigned)f2b(a) | ((unsigned)f2b(b) << 16);
}

// ---------------- setup kernels ----------------
__global__ void k_setup(int* __restrict__ counts, unsigned* __restrict__ flags,
                        float* __restrict__ partial, ArcT2* __restrict__ arcs,
                        unsigned* __restrict__ tickets)
{
    int i = blockIdx.x * blockDim.x + threadIdx.x;
    if (i < SS) counts[i] = 0;
    if (i < 2 * NBLK * FLGSTR) flags[i] = 0u;
    if (i < NG * 8) partial[i] = 0.f;
    if (i < 8) tickets[i] = 0u;
    if (i < EEPAD) { ArcT2 z; z.idx = 0; z.ew = 0.f; arcs[i] = z; }
}

__global__ void k_hist(const int* __restrict__ to_state, int* __restrict__ counts)
{
    int e = blockIdx.x * blockDim.x + threadIdx.x;
    if (e < EE) atomicAdd(&counts[to_state[e]], 1);
}

// prefix over counts padded to multiple of 8
__global__ void k_scan(const int* __restrict__ counts, int* __restrict__ rp,
                       int* __restrict__ cur)
{
    __shared__ int ls[1024];
    int tid = threadIdx.x;
    int s0 = tid * 3;
    int a0 = (s0 + 0 < SS) ? ((counts[s0 + 0] + 7) & ~7) : 0;
    int a1 = (s0 + 1 < SS) ? ((counts[s0 + 1] + 7) & ~7) : 0;
    int a2 = (s0 + 2 < SS) ? ((counts[s0 + 2] + 7) & ~7) : 0;
    int tsum = a0 + a1 + a2;
    ls[tid] = tsum;
    __syncthreads();
    for (int off = 1; off < 1024; off <<= 1) {
        int v = ls[tid];
        int add = (tid >= off) ? ls[tid - off] : 0;
        __syncthreads();
        ls[tid] = v + add;
        __syncthreads();
    }
    int excl = ls[tid] - tsum;
    if (s0 + 0 < SS) { rp[s0 + 0] = excl; cur[s0 + 0] = excl; }
    excl += a0;
    if (s0 + 1 < SS) { rp[s0 + 1] = excl; cur[s0 + 1] = excl; }
    excl += a1;
    if (s0 + 2 < SS) { rp[s0 + 2] = excl; cur[s0 + 2] = excl; }
    if (tid == 1023) rp[SS] = ls[1023];
}

// arc-balanced split into GB slices
__global__ void k_split(const int* __restrict__ rp, int* __restrict__ split)
{
    int j = threadIdx.x;
    if (j > GB) return;
    if (j == 0)  { split[0] = 0; return; }
    if (j == GB) { split[GB] = SS; return; }
    long long total = rp[SS];
    int target = (int)((total * j) / GB);
    int lo = 0, hi = SS;
    while (lo < hi) { int mid = (lo + hi) >> 1; if (rp[mid] >= target) hi = mid; else lo = mid + 1; }
    split[j] = lo;
}

__global__ void k_scatter(const int* __restrict__ from_state, const int* __restrict__ to_state,
                          const int* __restrict__ pdf_id, const float* __restrict__ trans_logw,
                          int* __restrict__ cur, ArcT2* __restrict__ arcs)
{
    int e = blockIdx.x * blockDim.x + threadIdx.x;
    if (e >= EE) return;
    int s = to_state[e];
    int pos = atomicAdd(&cur[s], 1);
    ArcT2 a;
    a.idx = (unsigned)from_state[e] | ((unsigned)pdf_id[e] << 16);
    a.ew = __expf(trans_logw[e]);
    arcs[pos] = a;
}

// ---------------- mega-kernel, measured-XCD groups (r10 body, launch-agnostic) ----------------
__global__ void __launch_bounds__(NT, 4) k_coop(
    const ArcT2* __restrict__ arcs, const int* __restrict__ rp,
    const int* __restrict__ split,
    const float* __restrict__ input, const float* __restrict__ init_logp,
    const float* __restrict__ final_logp,
    float* __restrict__ partial,         // [NG][8]
    unsigned* __restrict__ A_all,        // [NG][2][ASTRD] rows of 4 dwords (8xbf16)
    unsigned* __restrict__ flags,        // [2][NBLK][FLGSTR]
    unsigned* __restrict__ tickets,      // [8]
    float* __restrict__ out)
{
    extern __shared__ char dsm[];
    ArcT2*    larc  = (ArcT2*)(dsm + OFF_ARC);
    unsigned* la32  = (unsigned*)(dsm + OFF_ALPHA);   // [3000][4] packed bf16 x8
    unsigned* lex32 = (unsigned*)(dsm + OFF_EX);      // [2000][4]
    int*      rbp   = (int*)(dsm + OFF_RBP);
    float*    redf  = (float*)(dsm + OFF_RED);
    unsigned* sh    = (unsigned*)(dsm + OFF_SH);

    int tid = threadIdx.x, bid = blockIdx.x;
    int lane = tid & 63, wave = tid >> 6;
    int oct = lane >> 3, sub = lane & 7;

    unsigned* stepf = flags;
    unsigned* auxf  = flags + (size_t)NBLK * FLGSTR;

    // ---- measure XCD + take group ticket (placement-independent grouping) ----
    if (tid == 0) {
        unsigned x = __builtin_amdgcn_s_getreg(6164) & 7u;   // HW_REG_XCC_ID (verified r8)
        unsigned t = __hip_atomic_fetch_add(&tickets[x], 1u, __ATOMIC_RELAXED,
                                            __HIP_MEMORY_SCOPE_AGENT);
        sh[0] = x; sh[1] = t;
        __hip_atomic_store(auxf + (size_t)bid * FLGSTR, 1u,
                           __ATOMIC_RELAXED, __HIP_MEMORY_SCOPE_AGENT);
    }
    // global aux barrier #1: all 256 blocks ticketed
    if (wave == 0) {
        while (true) {
            unsigned ok = 1;
            #pragma unroll
            for (int r = 0; r < 4; ++r) {
                unsigned v = __hip_atomic_load(auxf + (size_t)(lane * 4 + r) * FLGSTR,
                                               __ATOMIC_RELAXED, __HIP_MEMORY_SCOPE_AGENT);
                ok &= (v >= 1u);
            }
            if (__ballot(ok != 0) == ~0ULL) break;
            __builtin_amdgcn_s_sleep(1);
        }
    }
    __syncthreads();
    // validity: every XCD group must have exactly 32 members
    if (tid == 0) {
        unsigned ok = 1;
        for (int q = 0; q < 8; ++q)
            ok &= (__hip_atomic_load(&tickets[q], __ATOMIC_RELAXED,
                                     __HIP_MEMORY_SCOPE_AGENT) == (unsigned)GB);
        sh[2] = ok;
    }
    __syncthreads();
    const bool fast = (sh[2] != 0);
    int g = fast ? (int)sh[0] : (bid & 7);
    int j = fast ? (int)(sh[1] & 31) : (bid >> 3);
    __syncthreads();

    unsigned* Ag       = A_all + (size_t)g * (2 * ASTRD);
    unsigned* myflag   = stepf + (size_t)(g * GB + j) * FLGSTR;
    unsigned* grpflag  = stepf + (size_t)(g * GB) * FLGSTR;
    unsigned* myflag2  = auxf + (size_t)(g * GB + j) * FLGSTR;
    unsigned* grpflag2 = auxf + (size_t)(g * GB) * FLGSTR;

    int s0 = split[j], s1 = split[j + 1];
    int nst = s1 - s0;
    if (nst > NSTMAX) nst = NSTMAX;                  // safety (never expected)

    // ---- stage rp slice + arcs to LDS; alpha0 (own slice) ----
    for (int i = tid; i <= nst; i += NT) rbp[i] = rp[s0 + i];
    __syncthreads();
    int rb0 = rbp[0];
    {
        int staged = rbp[nst] - rb0; if (staged > CAP) staged = CAP;
        for (int i = tid; i < staged; i += NT) larc[i] = arcs[rb0 + i];
    }
    for (int i = tid; i < nst; i += NT) {
        int s = s0 + i;
        unsigned short h = f2b(__expf(init_logp[s]));
        unsigned pk = (unsigned)h | ((unsigned)h << 16);
        if (fast) {
            uv4 v; v.x = pk; v.y = pk; v.z = pk; v.w = pk;
            *(uv4*)(Ag + s * 4) = v;
        } else {
            unsigned long long q = (unsigned long long)pk | ((unsigned long long)pk << 32);
            __hip_atomic_store((unsigned long long*)(Ag + s * 4), q,
                               __ATOMIC_RELAXED, __HIP_MEMORY_SCOPE_AGENT);
            __hip_atomic_store((unsigned long long*)(Ag + s * 4) + 1, q,
                               __ATOMIC_RELAXED, __HIP_MEMORY_SCOPE_AGENT);
        }
    }
    __syncthreads();                                 // larc ready; alpha0 stores drained
    if (tid == 0)
        __hip_atomic_store(myflag2, 2u, __ATOMIC_RELAXED, __HIP_MEMORY_SCOPE_AGENT);
    {   // ex frame 0 (overlaps other blocks' arrival)
        const float* fr = input + (size_t)(g * 8) * DD;
        for (int d = tid; d < DD; d += NT) {
            uv4 v;
            v.x = pack2(__expf(fr[0 * DD + d]), __expf(fr[1 * DD + d]));
            v.y = pack2(__expf(fr[2 * DD + d]), __expf(fr[3 * DD + d]));
            v.z = pack2(__expf(fr[4 * DD + d]), __expf(fr[5 * DD + d]));
            v.w = pack2(__expf(fr[6 * DD + d]), __expf(fr[7 * DD + d]));
            *(uv4*)(lex32 + d * 4) = v;
        }
    }
    if (wave == 0) {                                 // group barrier #2: alpha0 visible
        while (true) {
            unsigned v = 2;
            if (lane < GB)
                v = __hip_atomic_load(grpflag2 + lane * FLGSTR, __ATOMIC_RELAXED,
                                      __HIP_MEMORY_SCOPE_AGENT);
            if (__ballot(v >= 2) == ~0ULL) break;
            __builtin_amdgcn_s_sleep(1);
        }
    }
    __syncthreads();

    float vf[8];
    #pragma unroll
    for (int q = 0; q < 8; ++q) vf[q] = 0.f;

    unsigned ep = 0;

    // ---- 150 steps ----
    for (int k = 0; k < TT; ++k) {
        const unsigned* Ap32 = Ag + (k & 1) * ASTRD;
        unsigned*       An32 = Ag + ((k + 1) & 1) * ASTRD;
        bool last = (k == TT - 1);
        bool resc = (((k + 1) & (RESC - 1)) == 0);

        // phase A: alpha_k (48 KB) L2 -> LDS
        if (fast) {
            const uv4* Ap128 = (const uv4*)Ap32;
            for (int idx = tid; idx < SS; idx += NT) {
                uv4 v = *(volatile const uv4*)(Ap128 + idx);   // volatile -> sc0
                *((uv4*)la32 + idx) = v;
            }
        } else {
            const unsigned long long* Ap64 = (const unsigned long long*)Ap32;
            for (int idx = tid; idx < SS * 2; idx += NT) {
                unsigned long long v = __hip_atomic_load(Ap64 + idx, __ATOMIC_RELAXED,
                                                         __HIP_MEMORY_SCOPE_AGENT);
                la32[idx * 2 + 0] = (unsigned)v;
                la32[idx * 2 + 1] = (unsigned)(v >> 32);
            }
        }
        __syncthreads();

        // phase B: gather own states; lane=(oct=state slot, sub=arc sub)
        for (int base = 0; base < nst; base += 128) {
            int li = base + oct * 16 + wave;
            bool has = (li < nst);
            float acc[8];
            #pragma unroll
            for (int q = 0; q < 8; ++q) acc[q] = 0.f;
            int sg = 0;
            if (has) {
                sg = s0 + li;
                int ra = rbp[li], re = rbp[li + 1];
                int nit = (re - ra) >> 3;
                if (re - rb0 <= CAP) {
                    int bix = ra - rb0 + sub;
                    for (int t = 0; t < nit; ++t) {
                        ArcT2 a = larc[bix + t * 8];
                        uv4 av = *(const uv4*)(la32 + (a.idx & 0xFFFF) * 4);
                        uv4 ev = *(const uv4*)(lex32 + (a.idx >> 16) * 4);
                        float ew = a.ew;
                        #pragma unroll
                        for (int q = 0; q < 4; ++q) {
                            unsigned au = av[q], eu = ev[q];
                            acc[2 * q + 0] = fmaf(u2f(au << 16), ew * u2f(eu << 16),
                                                  acc[2 * q + 0]);
                            acc[2 * q + 1] = fmaf(u2f(au & 0xFFFF0000u),
                                                  ew * u2f(eu & 0xFFFF0000u),
                                                  acc[2 * q + 1]);
                        }
                    }
                } else {
                    for (int t = 0; t < nit; ++t) {  // safety overflow path
                        ArcT2 a = arcs[ra + t * 8 + sub];
                        uv4 av = *(const uv4*)(la32 + (a.idx & 0xFFFF) * 4);
                        uv4 ev = *(const uv4*)(lex32 + (a.idx >> 16) * 4);
                        float ew = a.ew;
                        #pragma unroll
                        for (int q = 0; q < 4; ++q) {
                            unsigned au = av[q], eu = ev[q];
                            acc[2 * q + 0] = fmaf(u2f(au << 16), ew * u2f(eu << 16),
                                                  acc[2 * q + 0]);
                            acc[2 * q + 1] = fmaf(u2f(au & 0xFFFF0000u),
                                                  ew * u2f(eu & 0xFFFF0000u),
                                                  acc[2 * q + 1]);
                        }
                    }
                }
            }
            #pragma unroll
            for (int q = 0; q < 8; ++q) {
                acc[q] += __shfl_xor(acc[q], 1, 64);
                acc[q] += __shfl_xor(acc[q], 2, 64);
                acc[q] += __shfl_xor(acc[q], 4, 64);
            }
            if (has && sub == 0) {
                if (resc) {
                    #pragma unroll
                    for (int q = 0; q < 8; ++q) acc[q] *= RESCC;
                }
                if (last) {
                    float ef = __expf(final_logp[sg]);
                    #pragma unroll
                    for (int q = 0; q < 8; ++q) vf[q] = fmaf(acc[q], ef, vf[q]);
                } else {
                    uv4 pk4;
                    pk4.x = pack2(acc[0], acc[1]);
                    pk4.y = pack2(acc[2], acc[3]);
                    pk4.z = pack2(acc[4], acc[5]);
                    pk4.w = pack2(acc[6], acc[7]);
                    if (fast) {
                        *(uv4*)(An32 + sg * 4) = pk4;
                    } else {
                        unsigned long long lo = (unsigned long long)pk4.x |
                                                ((unsigned long long)pk4.y << 32);
                        unsigned long long hi = (unsigned long long)pk4.z |
                                                ((unsigned long long)pk4.w << 32);
                        __hip_atomic_store((unsigned long long*)(An32 + sg * 4), lo,
                                           __ATOMIC_RELAXED, __HIP_MEMORY_SCOPE_AGENT);
                        __hip_atomic_store((unsigned long long*)(An32 + sg * 4) + 1, hi,
                                           __ATOMIC_RELAXED, __HIP_MEMORY_SCOPE_AGENT);
                    }
                }
            }
        }
        if (last) break;
        __syncthreads();                             // stores drained (vmcnt 0)
        ++ep;
        if (tid == 0) {
            if (fast) *(volatile unsigned*)myflag = ep;
            else __hip_atomic_store(myflag, ep, __ATOMIC_RELAXED, __HIP_MEMORY_SCOPE_AGENT);
        }
        {   // ex_{k+1} (independent of alpha) — overlaps others' arrival
            const float* fr = input + (size_t)((k + 1) * BB + g * 8) * DD;
            for (int d = tid; d < DD; d += NT) {
                uv4 v;
                v.x = pack2(__expf(fr[0 * DD + d]), __expf(fr[1 * DD + d]));
                v.y = pack2(__expf(fr[2 * DD + d]), __expf(fr[3 * DD + d]));
                v.z = pack2(__expf(fr[4 * DD + d]), __expf(fr[5 * DD + d]));
                v.w = pack2(__expf(fr[6 * DD + d]), __expf(fr[7 * DD + d]));
                *(uv4*)(lex32 + d * 4) = v;
            }
        }
        if (wave == 0) {
            while (true) {
                unsigned v = ep;
                if (lane < GB) {
                    v = fast ? *(volatile const unsigned*)(grpflag + lane * FLGSTR)
                             : __hip_atomic_load(grpflag + lane * FLGSTR, __ATOMIC_RELAXED,
                                                 __HIP_MEMORY_SCOPE_AGENT);
                }
                if (__ballot(v >= ep) == ~0ULL) break;
                __builtin_amdgcn_s_sleep(1);
            }
        }
        __syncthreads();
    }

    // ---- epilogue: reduce objf (8 batch) across block, then group ----
    #pragma unroll
    for (int q = 0; q < 8; ++q) {
        float v = vf[q];
        v += __shfl_xor(v, 1, 64);
        v += __shfl_xor(v, 2, 64);
        v += __shfl_xor(v, 4, 64);
        v += __shfl_xor(v, 8, 64);
        v += __shfl_xor(v, 16, 64);
        v += __shfl_xor(v, 32, 64);
        if (lane == 0) redf[wave * 8 + q] = v;
    }
    __syncthreads();
    if (tid < 8) {
        float S = 0.f;
        #pragma unroll
        for (int w = 0; w < 16; ++w) S += redf[w * 8 + tid];
        __hip_atomic_fetch_add(&partial[g * 8 + tid], S, __ATOMIC_RELAXED,
                               __HIP_MEMORY_SCOPE_AGENT);
    }
    __syncthreads();
    if (tid == 0)
        __hip_atomic_store(myflag2, 3u, __ATOMIC_RELAXED, __HIP_MEMORY_SCOPE_AGENT);
    if (j == 0) {
        if (wave == 0) {
            while (true) {
                unsigned v = 3;
                if (lane < GB)
                    v = __hip_atomic_load(grpflag2 + lane * FLGSTR, __ATOMIC_RELAXED,
                                          __HIP_MEMORY_SCOPE_AGENT);
                if (__ballot(v >= 3) == ~0ULL) break;
                __builtin_amdgcn_s_sleep(1);
            }
        }
        __syncthreads();
        if (tid < 8) {
            float S = __hip_atomic_load(&partial[g * 8 + tid], __ATOMIC_RELAXED,
                                        __HIP_MEMORY_SCOPE_AGENT);
            float lg = logf(S) + (float)(NSLOT * 46) * 0.69314718055994531f;
            atomicAdd(out, lg);
        }
    }
}

extern "C" void kernel_launch(void* const* d_in, const int* in_sizes, int n_in,
                              void* d_out, int out_size, void* d_ws, size_t ws_size,
                              hipStream_t stream)
{
    const float* input      = (const float*)d_in[0];
    const float* trans_logw = (const float*)d_in[1];
    const float* init_logp  = (const float*)d_in[2];
    const float* final_logp = (const float*)d_in[3];
    const int*   from_state = (const int*)d_in[4];
    const int*   to_state   = (const int*)d_in[5];
    const int*   pdf_id     = (const int*)d_in[6];
    float* out = (float*)d_out;

    char* ws = (char*)d_ws;
    size_t off = 0;
    auto alloc = [&](size_t bytes) -> char* {
        char* p = ws + off;
        off = (off + bytes + 255) & ~(size_t)255;
        return p;
    };
    ArcT2* arcs  = (ArcT2*)alloc((size_t)EEPAD * sizeof(ArcT2));
    int* rp      = (int*)alloc((size_t)(SS + 1) * 4);
    int* cur     = (int*)alloc((size_t)SS * 4);
    int* counts  = (int*)alloc((size_t)SS * 4);
    int* split   = (int*)alloc((size_t)(GB + 1) * 4);
    unsigned* A_all = (unsigned*)alloc((size_t)NG * 2 * ASTRD * 4);
    float* partial  = (float*)alloc((size_t)NG * 8 * 4);
    unsigned* flags = (unsigned*)alloc((size_t)2 * NBLK * FLGSTR * 4);
    unsigned* tickets = (unsigned*)alloc((size_t)8 * 4);
    (void)ws_size; (void)in_sizes; (void)n_in; (void)out_size;
    (void)trans_logw;

    k_setup<<<(EEPAD + 255) / 256, 256, 0, stream>>>(counts, flags, partial, arcs, tickets);
    k_hist<<<(EE + 255) / 256, 256, 0, stream>>>(to_state, counts);
    k_scan<<<1, 1024, 0, stream>>>(counts, rp, cur);
    k_split<<<1, 64, 0, stream>>>(rp, split);
    k_scatter<<<(EE + 255) / 256, 256, 0, stream>>>(from_state, to_state, pdf_id,
                                                    trans_logw, cur, arcs);
    hipMemsetAsync(d_out, 0, sizeof(float), stream);

    hipFuncSetAttribute((const void*)k_coop, hipFuncAttributeMaxDynamicSharedMemorySize,
                        DYNLDS);

    // Try cooperative launch first (guaranteed co-residency when it works).
    {
        void* kp[11] = {
            (void*)&arcs, (void*)&rp, (void*)&split, (void*)&input, (void*)&init_logp,
            (void*)&final_logp, (void*)&partial, (void*)&A_all, (void*)&flags,
            (void*)&tickets, (void*)&out
        };
        hipError_t e = hipLaunchCooperativeKernel((const void*)k_coop, dim3(NBLK), dim3(NT),
                                                  kp, DYNLDS, stream);
        if (e == hipSuccess) return;
    }
    // Coop launch rejected (observed flakily during graph capture, r3/r9/r10):
    // plain launch of the SAME kernel. Co-residency is structural: 121.6 KB LDS
    // forces 1 block/CU and grid == 256 == #CUs; the kernel's ticket-based
    // grouping is placement-independent, and the slow (agent-scope) protocol
    // inside covers any non-uniform XCD distribution.
    k_coop<<<dim3(NBLK), dim3(NT), DYNLDS, stream>>>(
        arcs, rp, split, input, init_logp, final_logp,
        partial, A_all, flags, tickets, out);
}